// Round 7
// baseline (1054.629 us; speedup 1.0000x reference)
//
#include <hip/hip_runtime.h>

// FBSNN loss — fused producer/consumer, bf16 MFMA, permuted-k layout.
//
// Fused kernel: 640 blocks x 64 threads (1 wave each, 36KB LDS each) ->
//   all co-resident in ANY dispatch order (per-CU: 4 blocks by LDS, 4 waves).
//   Blocks 0..127   = producers: sequential q-net scan, 32 paths/wave.
//   Blocks 128..639 = consumers: Y-net + tangent for 32-point tiles, polling
//                     per-step release/acquire counters (device scope).
// Weight A-frags are hoisted from LDS into registers and LAUNDERED through an
// empty asm so the allocator cannot rematerialize the LDS loads (round-4/5/6
// failure mode: VGPR_Count=132, frags re-read on the serial chain).
// Permuted-k (swap bits 2<->3 of k) makes layer transitions pure sin+pack,
// zero cross-lane ops (validated round 6).
// Phase 3: residuals + reduction (separate kernel).

#define NPATH   4096
#define NSTEP   50
#define DT_F    0.02f
#define SQRT_DT 0.14142136f
#define SIGMA_F 0.5f
#define NWT     6528        // 51*4096/32 wave-tiles
#define NCONS   512

typedef __attribute__((ext_vector_type(8)))  short s16x8;
typedef __attribute__((ext_vector_type(16))) float f32x16;

__device__ __forceinline__ unsigned pkbf(float a, float b) {
    unsigned ua = __float_as_uint(a), ub = __float_as_uint(b);
    ua += 0x7fffu + ((ua >> 16) & 1u);
    ub += 0x7fffu + ((ub >> 16) & 1u);
    return (ua >> 16) | (ub & 0xffff0000u);
}

__device__ __forceinline__ s16x8 frag4(unsigned a, unsigned b, unsigned c, unsigned d) {
    union { unsigned u[4]; s16x8 s; } x;
    x.u[0] = a; x.u[1] = b; x.u[2] = c; x.u[3] = d;
    return x.s;
}

// opaque def: compiler cannot rematerialize the LDS read through this asm
__device__ __forceinline__ s16x8 launder_frag(uint4 v) {
    unsigned a = v.x, b = v.y, c = v.z, d = v.w;
    asm("" : "+v"(a), "+v"(b), "+v"(c), "+v"(d));
    return frag4(a, b, c, d);
}

__device__ __forceinline__ f32x16 zf() {
    f32x16 v;
#pragma unroll
    for (int i = 0; i < 16; ++i) v[i] = 0.0f;
    return v;
}

// ---- frag table builder, PERMUTED k (swap bits 2<->3 of k) ----
// e=0..1: input (tau=e); e=2..31: hidden (2+L*10+tau*5+b, b=4 is bias);
// e=32..35: Wout k-blocks.
__device__ __forceinline__ void build_frags(
    const float* __restrict__ Win, const float* __restrict__ bin,
    const float* __restrict__ Whid, const float* __restrict__ bhid,
    const float* __restrict__ Wout,
    uint4* __restrict__ fragLDS, int l, int h, int m, int e0, int estep)
{
    for (int e = e0; e < 36; e += estep) {
        unsigned w0 = 0, w1 = 0, w2 = 0, w3 = 0;
        if (e < 2) {                     // input layer: k0=t, k1=y, k2=bias (no perm)
            int u = 32 * e + m;
            if (h == 0) {
                w0 = pkbf(Win[u], Win[64 + u]);
                w1 = pkbf(bin[u], 0.0f);
            }
        } else if (e < 32) {
            int e2 = e - 2;
            int L = e2 / 10, rem = e2 % 10;
            int tau = rem / 5, b = rem % 5;
            int u = 32 * tau + m;
            if (b < 4) {
                int k0 = 16 * b + 4 * h;
                const float* Wp = Whid + L * 4096 + u;
                w0 = pkbf(Wp[(k0 + 0)  * 64], Wp[(k0 + 1)  * 64]);
                w1 = pkbf(Wp[(k0 + 2)  * 64], Wp[(k0 + 3)  * 64]);
                w2 = pkbf(Wp[(k0 + 8)  * 64], Wp[(k0 + 9)  * 64]);
                w3 = pkbf(Wp[(k0 + 10) * 64], Wp[(k0 + 11) * 64]);
            } else {
                if (h == 0) w0 = pkbf(bhid[L * 64 + u], 0.0f);   // bias at k=0
            }
        } else {
            int b = e - 32;
            if (m == 0) {
                int k0 = 16 * b + 4 * h;
                w0 = pkbf(Wout[k0 + 0],  Wout[k0 + 1]);
                w1 = pkbf(Wout[k0 + 2],  Wout[k0 + 3]);
                w2 = pkbf(Wout[k0 + 8],  Wout[k0 + 9]);
                w3 = pkbf(Wout[k0 + 10], Wout[k0 + 11]);
            }
        }
        fragLDS[e * 64 + l] = make_uint4(w0, w1, w2, w3);
    }
}

// fwd-only transition, no cross-lane ops
__device__ __forceinline__ void trans_fwd(const f32x16& C0, const f32x16& C1,
                                          s16x8* Bf)
{
    float a0[16], a1[16];
#pragma unroll
    for (int r = 0; r < 16; ++r) { a0[r] = __sinf(C0[r]); a1[r] = __sinf(C1[r]); }
#pragma unroll
    for (int b = 0; b < 4; ++b) {
        const float* A = (b & 2) ? a1 : a0;
        unsigned w[4];
#pragma unroll
        for (int j = 0; j < 4; ++j) {
            const int rb = 2 * (j & 1) + 4 * (j >> 1) + 8 * (b & 1);
            w[j] = pkbf(A[rb], A[rb + 1]);
        }
        Bf[b] = frag4(w[0], w[1], w[2], w[3]);
    }
}

// fwd+tangent transition, no cross-lane ops
__device__ __forceinline__ void trans_tan(
    const f32x16& Cf0, const f32x16& Cf1, const f32x16& Ct0, const f32x16& Ct1,
    s16x8* Bf, s16x8* Bt)
{
    float sf0[16], sf1[16], st0[16], st1[16];
#pragma unroll
    for (int r = 0; r < 16; ++r) {
        float s, c;
        __sincosf(Cf0[r], &s, &c); sf0[r] = s; st0[r] = c * Ct0[r];
    }
#pragma unroll
    for (int r = 0; r < 16; ++r) {
        float s, c;
        __sincosf(Cf1[r], &s, &c); sf1[r] = s; st1[r] = c * Ct1[r];
    }
#pragma unroll
    for (int b = 0; b < 4; ++b) {
        const float* F = (b & 2) ? sf1 : sf0;
        const float* T = (b & 2) ? st1 : st0;
        unsigned wf[4], wt[4];
#pragma unroll
        for (int j = 0; j < 4; ++j) {
            const int rb = 2 * (j & 1) + 4 * (j >> 1) + 8 * (b & 1);
            wf[j] = pkbf(F[rb], F[rb + 1]);
            wt[j] = pkbf(T[rb], T[rb + 1]);
        }
        Bf[b] = frag4(wf[0], wf[1], wf[2], wf[3]);
        Bt[b] = frag4(wt[0], wt[1], wt[2], wt[3]);
    }
}

// ================= fused producer/consumer kernel =================

extern "C" __global__ void __launch_bounds__(64, 1)
fbsnn_fused(const float* __restrict__ Y_Win, const float* __restrict__ Y_bin,
            const float* __restrict__ Y_Whid, const float* __restrict__ Y_bhid,
            const float* __restrict__ Y_Wout, const float* __restrict__ Y_bout,
            const float* __restrict__ q_Win, const float* __restrict__ q_bin,
            const float* __restrict__ q_Whid, const float* __restrict__ q_bhid,
            const float* __restrict__ q_Wout, const float* __restrict__ q_bout,
            const float* __restrict__ y0p, const float* __restrict__ dW,
            float* __restrict__ y_ws, float* __restrict__ q_ws,
            float* __restrict__ Y_ws, float* __restrict__ dY_ws,
            unsigned* __restrict__ cnt)
{
    __shared__ uint4 fragLDS[36 * 64];

    const int l = (int)(threadIdx.x & 63);
    const int h = l >> 5;
    const int m = l & 31;
    const bool prod = (blockIdx.x < 128);

    build_frags(prod ? q_Win  : Y_Win,  prod ? q_bin  : Y_bin,
                prod ? q_Whid : Y_Whid, prod ? q_bhid : Y_bhid,
                prod ? q_Wout : Y_Wout, fragLDS, l, h, m, 0, 1);
    __syncthreads();

    // hoist + launder: frags become opaque register-resident values
    s16x8 F[36];
#pragma unroll
    for (int e = 0; e < 36; ++e) F[e] = launder_frag(fragLDS[e * 64 + l]);

    const float bo   = prod ? q_bout[0] : Y_bout[0];
    const s16x8 Bone = frag4(h ? 0u : pkbf(1.0f, 0.0f), 0u, 0u, 0u);

    if (prod) {
        // ---------------- producer: sequential q-net scan ----------------
        const int p = (int)blockIdx.x * 32 + m;
        float y = y0p[0];
        float dw_cur = dW[p];

        for (int n = 0; n < NSTEP; ++n) {
            const float t = n * DT_F;
            if (h == 0)
                __hip_atomic_store(&y_ws[n * NPATH + p], y,
                                   __ATOMIC_RELAXED, __HIP_MEMORY_SCOPE_AGENT);

            const int n1 = (n + 1 < NSTEP) ? n + 1 : NSTEP - 1;
            const float dw_next = dW[n1 * NPATH + p];

            const s16x8 Bty = frag4(h ? 0u : pkbf(t, y),
                                    h ? 0u : pkbf(1.0f, 0.0f), 0u, 0u);

            f32x16 C0 = zf(), C1 = zf();
            C0 = __builtin_amdgcn_mfma_f32_32x32x16_bf16(F[0], Bty, C0, 0, 0, 0);
            C1 = __builtin_amdgcn_mfma_f32_32x32x16_bf16(F[1], Bty, C1, 0, 0, 0);
            s16x8 Bf[4];
            trans_fwd(C0, C1, Bf);

#pragma unroll
            for (int L = 0; L < 3; ++L) {
                const int base = 2 + L * 10;
                C0 = zf(); C1 = zf();
                C0 = __builtin_amdgcn_mfma_f32_32x32x16_bf16(F[base + 4], Bone, C0, 0, 0, 0);
                C1 = __builtin_amdgcn_mfma_f32_32x32x16_bf16(F[base + 9], Bone, C1, 0, 0, 0);
#pragma unroll
                for (int b = 0; b < 4; ++b) {
                    C0 = __builtin_amdgcn_mfma_f32_32x32x16_bf16(F[base + b],     Bf[b], C0, 0, 0, 0);
                    C1 = __builtin_amdgcn_mfma_f32_32x32x16_bf16(F[base + 5 + b], Bf[b], C1, 0, 0, 0);
                }
                trans_fwd(C0, C1, Bf);
            }

            f32x16 Co = zf();
#pragma unroll
            for (int b = 0; b < 4; ++b)
                Co = __builtin_amdgcn_mfma_f32_32x32x16_bf16(F[32 + b], Bf[b], Co, 0, 0, 0);

            const float q = Co[0] + bo;              // valid at h==0, col=m
            if (h == 0) q_ws[n * NPATH + p] = q;
            y = fmaf(q, DT_F, y) + SIGMA_F * (dw_cur * SQRT_DT);
            dw_cur = dw_next;

            // release step n (its y_ws was stored at loop top; fence's vmcnt
            // wait overlapped with the q-net compute above)
            __threadfence();
            if (l == 0)
                __hip_atomic_fetch_add(&cnt[n], 1u,
                                       __ATOMIC_RELEASE, __HIP_MEMORY_SCOPE_AGENT);
        }
        if (h == 0)
            __hip_atomic_store(&y_ws[NSTEP * NPATH + p], y,
                               __ATOMIC_RELAXED, __HIP_MEMORY_SCOPE_AGENT);
        __threadfence();
        if (l == 0)
            __hip_atomic_fetch_add(&cnt[NSTEP], 1u,
                                   __ATOMIC_RELEASE, __HIP_MEMORY_SCOPE_AGENT);
    } else {
        // ---------------- consumer: Y-net + tangent tiles ----------------
        const int c = (int)blockIdx.x - 128;
        const s16x8 Btn = frag4(h ? 0u : pkbf(0.0f, 1.0f), 0u, 0u, 0u);

        for (int wt = c; wt < NWT; wt += NCONS) {
            const int n = wt >> 7;                   // 128 wave-tiles per step
            while (__hip_atomic_load(&cnt[n], __ATOMIC_ACQUIRE,
                                     __HIP_MEMORY_SCOPE_AGENT) < 128u)
                __builtin_amdgcn_s_sleep(8);

            const int point = wt * 32 + m;
            const float t = n * DT_F;
            const float y = __hip_atomic_load(&y_ws[point], __ATOMIC_RELAXED,
                                              __HIP_MEMORY_SCOPE_AGENT);

            const s16x8 Bty = frag4(h ? 0u : pkbf(t, y),
                                    h ? 0u : pkbf(1.0f, 0.0f), 0u, 0u);

            f32x16 Cf0 = zf(), Cf1 = zf(), Ct0 = zf(), Ct1 = zf();
            Cf0 = __builtin_amdgcn_mfma_f32_32x32x16_bf16(F[0], Bty, Cf0, 0, 0, 0);
            Cf1 = __builtin_amdgcn_mfma_f32_32x32x16_bf16(F[1], Bty, Cf1, 0, 0, 0);
            Ct0 = __builtin_amdgcn_mfma_f32_32x32x16_bf16(F[0], Btn, Ct0, 0, 0, 0);
            Ct1 = __builtin_amdgcn_mfma_f32_32x32x16_bf16(F[1], Btn, Ct1, 0, 0, 0);
            s16x8 Bf[4], Bt[4];
            trans_tan(Cf0, Cf1, Ct0, Ct1, Bf, Bt);

#pragma unroll
            for (int L = 0; L < 3; ++L) {
                const int base = 2 + L * 10;
                Cf0 = zf(); Cf1 = zf(); Ct0 = zf(); Ct1 = zf();
                Cf0 = __builtin_amdgcn_mfma_f32_32x32x16_bf16(F[base + 4], Bone, Cf0, 0, 0, 0);
                Cf1 = __builtin_amdgcn_mfma_f32_32x32x16_bf16(F[base + 9], Bone, Cf1, 0, 0, 0);
#pragma unroll
                for (int b = 0; b < 4; ++b) {
                    Cf0 = __builtin_amdgcn_mfma_f32_32x32x16_bf16(F[base + b],     Bf[b], Cf0, 0, 0, 0);
                    Ct0 = __builtin_amdgcn_mfma_f32_32x32x16_bf16(F[base + b],     Bt[b], Ct0, 0, 0, 0);
                    Cf1 = __builtin_amdgcn_mfma_f32_32x32x16_bf16(F[base + 5 + b], Bf[b], Cf1, 0, 0, 0);
                    Ct1 = __builtin_amdgcn_mfma_f32_32x32x16_bf16(F[base + 5 + b], Bt[b], Ct1, 0, 0, 0);
                }
                trans_tan(Cf0, Cf1, Ct0, Ct1, Bf, Bt);
            }

            f32x16 Cof = zf(), Cot = zf();
#pragma unroll
            for (int b = 0; b < 4; ++b) {
                Cof = __builtin_amdgcn_mfma_f32_32x32x16_bf16(F[32 + b], Bf[b], Cof, 0, 0, 0);
                Cot = __builtin_amdgcn_mfma_f32_32x32x16_bf16(F[32 + b], Bt[b], Cot, 0, 0, 0);
            }
            if (h == 0) {
                Y_ws[point]  = Cof[0] + bo;
                dY_ws[point] = Cot[0];
            }
        }
    }
}

// ================= Phase 3: residuals + reduction =================
// grid.x: path blocks (16), grid.y: step chunks of 10 (5)

extern "C" __global__ void __launch_bounds__(256)
fbsnn_phase3(const float* __restrict__ y_ws, const float* __restrict__ q_ws,
             const float* __restrict__ Y_ws, const float* __restrict__ dY_ws,
             const float* __restrict__ dW, float* __restrict__ out)
{
    const int p  = blockIdx.x * 256 + threadIdx.x;
    const int n0 = blockIdx.y * 10;

    float acc = 0.0f;
    float Yc  = Y_ws[n0 * NPATH + p];
#pragma unroll
    for (int k = 0; k < 10; ++k) {
        const int n = n0 + k;
        float q    = q_ws[n * NPATH + p];
        float dYc  = dY_ws[n * NPATH + p];
        float dws  = dW[n * NPATH + p] * SQRT_DT;
        float Yn   = Y_ws[(n + 1) * NPATH + p];
        float Ytil = fmaf(-q * q, DT_F, Yc) + (SIGMA_F * dYc) * dws;
        float r    = Yn - Ytil;
        acc = fmaf(r, r, acc);
        Yc = Yn;
    }
    if (blockIdx.y == 4) {
        float y50  = y_ws[NSTEP * NPATH + p];
        float dY50 = dY_ws[NSTEP * NPATH + p];
        float r1 = Yc - y50 * y50;
        float r2 = dY50 - 2.0f * y50;
        acc = fmaf(r1, r1, fmaf(r2, r2, acc));
    }

    float v = acc;
#pragma unroll
    for (int off = 32; off > 0; off >>= 1) v += __shfl_down(v, off, 64);
    if ((threadIdx.x & 63) == 0) atomicAdd(out, v * (1.0f / (float)NPATH));
}

// ================= host launch =================

extern "C" void kernel_launch(void* const* d_in, const int* in_sizes, int n_in,
                              void* d_out, int out_size, void* d_ws, size_t ws_size,
                              hipStream_t stream)
{
    const float* Y_Win  = (const float*)d_in[0];
    const float* Y_bin  = (const float*)d_in[1];
    const float* Y_Whid = (const float*)d_in[2];
    const float* Y_bhid = (const float*)d_in[3];
    const float* Y_Wout = (const float*)d_in[4];
    const float* Y_bout = (const float*)d_in[5];
    const float* q_Win  = (const float*)d_in[6];
    const float* q_bin  = (const float*)d_in[7];
    const float* q_Whid = (const float*)d_in[8];
    const float* q_bhid = (const float*)d_in[9];
    const float* q_Wout = (const float*)d_in[10];
    const float* q_bout = (const float*)d_in[11];
    const float* y0p    = (const float*)d_in[12];
    const float* dW     = (const float*)d_in[13];

    float* ws    = (float*)d_ws;
    float* y_ws  = ws;                          // 51*4096
    float* q_ws  = ws + 51 * NPATH;             // 50*4096
    float* Y_ws  = ws + 101 * NPATH;            // 51*4096
    float* dY_ws = ws + 152 * NPATH;            // 51*4096
    unsigned* cnt = (unsigned*)(ws + 203 * NPATH);  // 51 step counters

    hipMemsetAsync(d_out, 0, sizeof(float), stream);
    hipMemsetAsync(cnt, 0, 64 * sizeof(unsigned), stream);

    fbsnn_fused<<<dim3(128 + NCONS), dim3(64), 0, stream>>>(
        Y_Win, Y_bin, Y_Whid, Y_bhid, Y_Wout, Y_bout,
        q_Win, q_bin, q_Whid, q_bhid, q_Wout, q_bout,
        y0p, dW, y_ws, q_ws, Y_ws, dY_ws, cnt);

    fbsnn_phase3<<<dim3(NPATH / 256, 5), dim3(256), 0, stream>>>(
        y_ws, q_ws, Y_ws, dY_ws, dW, (float*)d_out);
}

// Round 8
// 236.470 us; speedup vs baseline: 4.4599x; 4.4599x over previous
//
#include <hip/hip_runtime.h>

// FBSNN loss — bf16 MFMA, permuted-k layout (no cross-lane exchange).
// Round 8 = round 6 structure + asm-laundered register-resident frags in the
// sequential phase (validated in r7: laundering defeats LDS-remat, VGPR>=144).
// Fusion (r7) reverted: per-step agent fences + cross-XCD polling cost 4.5x.
//
// Phase 1: sequential q-net scan. 128 blocks x 64 thr (1 wave = 32 paths).
//          All 36 weight A-frags hoisted LDS->registers, laundered through an
//          empty asm so they cannot be rematerialized into the 50-step chain.
// Phase 2: Y-net + tangent at 51*4096 points, 408 blocks x 4 waves x 4 tiles.
// Phase 3: residuals + reduction, parallel over paths and step-chunks.

#define NPATH   4096
#define NSTEP   50
#define DT_F    0.02f
#define SQRT_DT 0.14142136f
#define SIGMA_F 0.5f

typedef __attribute__((ext_vector_type(8)))  short s16x8;
typedef __attribute__((ext_vector_type(16))) float f32x16;

__device__ __forceinline__ unsigned pkbf(float a, float b) {
    unsigned ua = __float_as_uint(a), ub = __float_as_uint(b);
    ua += 0x7fffu + ((ua >> 16) & 1u);
    ub += 0x7fffu + ((ub >> 16) & 1u);
    return (ua >> 16) | (ub & 0xffff0000u);
}

__device__ __forceinline__ s16x8 frag4(unsigned a, unsigned b, unsigned c, unsigned d) {
    union { unsigned u[4]; s16x8 s; } x;
    x.u[0] = a; x.u[1] = b; x.u[2] = c; x.u[3] = d;
    return x.s;
}

__device__ __forceinline__ s16x8 frag_of(uint4 v) {
    union { uint4 q; s16x8 s; } x; x.q = v; return x.s;
}

// opaque def: compiler cannot rematerialize the LDS read through this asm
__device__ __forceinline__ s16x8 launder_frag(uint4 v) {
    unsigned a = v.x, b = v.y, c = v.z, d = v.w;
    asm("" : "+v"(a), "+v"(b), "+v"(c), "+v"(d));
    return frag4(a, b, c, d);
}

__device__ __forceinline__ f32x16 zf() {
    f32x16 v;
#pragma unroll
    for (int i = 0; i < 16; ++i) v[i] = 0.0f;
    return v;
}

// ---- frag table builder, PERMUTED k (swap bits 2<->3 of k) ----
// e=0..1: input (tau=e); e=2..31: hidden (2+L*10+tau*5+b, b=4 is bias);
// e=32..35: Wout k-blocks. Hidden/out element (h,b,i) holds input-unit
// u_in = 16b + 4h + (i&3) + 8*(i>>2).
__device__ __forceinline__ void build_frags(
    const float* __restrict__ Win, const float* __restrict__ bin,
    const float* __restrict__ Whid, const float* __restrict__ bhid,
    const float* __restrict__ Wout,
    uint4* __restrict__ fragLDS, int l, int h, int m, int e0, int estep)
{
    for (int e = e0; e < 36; e += estep) {
        unsigned w0 = 0, w1 = 0, w2 = 0, w3 = 0;
        if (e < 2) {                     // input layer: k0=t, k1=y, k2=bias (no perm)
            int u = 32 * e + m;
            if (h == 0) {
                w0 = pkbf(Win[u], Win[64 + u]);
                w1 = pkbf(bin[u], 0.0f);
            }
        } else if (e < 32) {
            int e2 = e - 2;
            int L = e2 / 10, rem = e2 % 10;
            int tau = rem / 5, b = rem % 5;
            int u = 32 * tau + m;
            if (b < 4) {
                int k0 = 16 * b + 4 * h;
                const float* Wp = Whid + L * 4096 + u;
                w0 = pkbf(Wp[(k0 + 0)  * 64], Wp[(k0 + 1)  * 64]);
                w1 = pkbf(Wp[(k0 + 2)  * 64], Wp[(k0 + 3)  * 64]);
                w2 = pkbf(Wp[(k0 + 8)  * 64], Wp[(k0 + 9)  * 64]);
                w3 = pkbf(Wp[(k0 + 10) * 64], Wp[(k0 + 11) * 64]);
            } else {
                if (h == 0) w0 = pkbf(bhid[L * 64 + u], 0.0f);   // bias at k=0
            }
        } else {
            int b = e - 32;
            if (m == 0) {
                int k0 = 16 * b + 4 * h;
                w0 = pkbf(Wout[k0 + 0],  Wout[k0 + 1]);
                w1 = pkbf(Wout[k0 + 2],  Wout[k0 + 3]);
                w2 = pkbf(Wout[k0 + 8],  Wout[k0 + 9]);
                w3 = pkbf(Wout[k0 + 10], Wout[k0 + 11]);
            }
        }
        fragLDS[e * 64 + l] = make_uint4(w0, w1, w2, w3);
    }
}

// fwd-only transition, no cross-lane ops: Bf from own C regs
__device__ __forceinline__ void trans_fwd(const f32x16& C0, const f32x16& C1,
                                          s16x8* Bf)
{
    float a0[16], a1[16];
#pragma unroll
    for (int r = 0; r < 16; ++r) { a0[r] = __sinf(C0[r]); a1[r] = __sinf(C1[r]); }
#pragma unroll
    for (int b = 0; b < 4; ++b) {
        const float* A = (b & 2) ? a1 : a0;
        unsigned w[4];
#pragma unroll
        for (int j = 0; j < 4; ++j) {
            const int rb = 2 * (j & 1) + 4 * (j >> 1) + 8 * (b & 1);
            w[j] = pkbf(A[rb], A[rb + 1]);
        }
        Bf[b] = frag4(w[0], w[1], w[2], w[3]);
    }
}

// fwd+tangent transition, no cross-lane ops
__device__ __forceinline__ void trans_tan(
    const f32x16& Cf0, const f32x16& Cf1, const f32x16& Ct0, const f32x16& Ct1,
    s16x8* Bf, s16x8* Bt)
{
    float sf0[16], sf1[16], st0[16], st1[16];
#pragma unroll
    for (int r = 0; r < 16; ++r) {
        float s, c;
        __sincosf(Cf0[r], &s, &c); sf0[r] = s; st0[r] = c * Ct0[r];
    }
#pragma unroll
    for (int r = 0; r < 16; ++r) {
        float s, c;
        __sincosf(Cf1[r], &s, &c); sf1[r] = s; st1[r] = c * Ct1[r];
    }
#pragma unroll
    for (int b = 0; b < 4; ++b) {
        const float* F = (b & 2) ? sf1 : sf0;
        const float* T = (b & 2) ? st1 : st0;
        unsigned wf[4], wt[4];
#pragma unroll
        for (int j = 0; j < 4; ++j) {
            const int rb = 2 * (j & 1) + 4 * (j >> 1) + 8 * (b & 1);
            wf[j] = pkbf(F[rb], F[rb + 1]);
            wt[j] = pkbf(T[rb], T[rb + 1]);
        }
        Bf[b] = frag4(wf[0], wf[1], wf[2], wf[3]);
        Bt[b] = frag4(wt[0], wt[1], wt[2], wt[3]);
    }
}

// ================= Phase 1: q-net scan =================

extern "C" __global__ void __launch_bounds__(64, 1)
fbsnn_phase1(const float* __restrict__ q_Win, const float* __restrict__ q_bin,
             const float* __restrict__ q_Whid, const float* __restrict__ q_bhid,
             const float* __restrict__ q_Wout, const float* __restrict__ q_bout,
             const float* __restrict__ y0p, const float* __restrict__ dW,
             float* __restrict__ y_ws, float* __restrict__ q_ws)
{
    __shared__ uint4 fragLDS[36 * 64];

    const int l = (int)(threadIdx.x & 63);
    const int h = l >> 5;
    const int m = l & 31;
    const int p = (int)blockIdx.x * 32 + m;

    build_frags(q_Win, q_bin, q_Whid, q_bhid, q_Wout, fragLDS, l, h, m, 0, 1);
    __syncthreads();

    // hoist + launder: frags become opaque register-resident values (144 VGPR
    // forced live; budget 512 at launch_bounds(64,1))
    s16x8 F[36];
#pragma unroll
    for (int e = 0; e < 36; ++e) F[e] = launder_frag(fragLDS[e * 64 + l]);

    const float qb = q_bout[0];
    const s16x8 Bone = frag4(h ? 0u : pkbf(1.0f, 0.0f), 0u, 0u, 0u);

    float y = y0p[0];
    float dw_cur = dW[p];

    for (int n = 0; n < NSTEP; ++n) {
        const float t = n * DT_F;
        if (h == 0) y_ws[n * NPATH + p] = y;

        const int n1 = (n + 1 < NSTEP) ? n + 1 : NSTEP - 1;
        const float dw_next = dW[n1 * NPATH + p];

        const s16x8 Bty = frag4(h ? 0u : pkbf(t, y), h ? 0u : pkbf(1.0f, 0.0f), 0u, 0u);

        // input layer
        f32x16 C0 = zf(), C1 = zf();
        C0 = __builtin_amdgcn_mfma_f32_32x32x16_bf16(F[0], Bty, C0, 0, 0, 0);
        C1 = __builtin_amdgcn_mfma_f32_32x32x16_bf16(F[1], Bty, C1, 0, 0, 0);
        s16x8 Bf[4];
        trans_fwd(C0, C1, Bf);

        // hidden layers: bias-seeded single accumulator per tile
#pragma unroll
        for (int L = 0; L < 3; ++L) {
            const int base = 2 + L * 10;
            C0 = zf(); C1 = zf();
            C0 = __builtin_amdgcn_mfma_f32_32x32x16_bf16(F[base + 4], Bone, C0, 0, 0, 0);
            C1 = __builtin_amdgcn_mfma_f32_32x32x16_bf16(F[base + 9], Bone, C1, 0, 0, 0);
#pragma unroll
            for (int b = 0; b < 4; ++b) {
                C0 = __builtin_amdgcn_mfma_f32_32x32x16_bf16(F[base + b],     Bf[b], C0, 0, 0, 0);
                C1 = __builtin_amdgcn_mfma_f32_32x32x16_bf16(F[base + 5 + b], Bf[b], C1, 0, 0, 0);
            }
            trans_fwd(C0, C1, Bf);
        }

        // output layer
        f32x16 Co = zf();
#pragma unroll
        for (int b = 0; b < 4; ++b)
            Co = __builtin_amdgcn_mfma_f32_32x32x16_bf16(F[32 + b], Bf[b], Co, 0, 0, 0);

        const float q = Co[0] + qb;                  // valid at h==0, col=m
        if (h == 0) q_ws[n * NPATH + p] = q;
        y = fmaf(q, DT_F, y) + SIGMA_F * (dw_cur * SQRT_DT);
        dw_cur = dw_next;
    }
    if (h == 0) y_ws[NSTEP * NPATH + p] = y;
}

// ================= Phase 2: Y-net + tangent =================

#define NTILES 1632          // 208896 points / 128 per block
#define P2GRID 408           // 4 tiles per block exactly

extern "C" __global__ void __launch_bounds__(256, 2)
fbsnn_phase2(const float* __restrict__ Y_Win, const float* __restrict__ Y_bin,
             const float* __restrict__ Y_Whid, const float* __restrict__ Y_bhid,
             const float* __restrict__ Y_Wout, const float* __restrict__ Y_bout,
             const float* __restrict__ y_ws, float* __restrict__ Y_ws,
             float* __restrict__ dY_ws)
{
    __shared__ uint4 fragLDS[36 * 64];

    const int tid = (int)threadIdx.x;
    const int wv  = tid >> 6;
    const int l   = tid & 63;
    const int h   = l >> 5;
    const int m   = l & 31;

    build_frags(Y_Win, Y_bin, Y_Whid, Y_bhid, Y_Wout, fragLDS, l, h, m, wv, 4);
    __syncthreads();

    const float bout = Y_bout[0];
    const s16x8 Btn  = frag4(h ? 0u : pkbf(0.0f, 1.0f), 0u, 0u, 0u);
    const s16x8 Bone = frag4(h ? 0u : pkbf(1.0f, 0.0f), 0u, 0u, 0u);

    for (int tile = (int)blockIdx.x; tile < NTILES; tile += P2GRID) {
        const int point = tile * 128 + wv * 32 + m;
        const int n = point >> 12;
        const float t = n * DT_F;
        const float y = y_ws[point];

        const s16x8 Bty = frag4(h ? 0u : pkbf(t, y), h ? 0u : pkbf(1.0f, 0.0f), 0u, 0u);

        f32x16 Cf0 = zf(), Cf1 = zf(), Ct0 = zf(), Ct1 = zf();
        {
            s16x8 A0 = frag_of(fragLDS[0 * 64 + l]);
            s16x8 A1 = frag_of(fragLDS[1 * 64 + l]);
            Cf0 = __builtin_amdgcn_mfma_f32_32x32x16_bf16(A0, Bty, Cf0, 0, 0, 0);
            Cf1 = __builtin_amdgcn_mfma_f32_32x32x16_bf16(A1, Bty, Cf1, 0, 0, 0);
            Ct0 = __builtin_amdgcn_mfma_f32_32x32x16_bf16(A0, Btn, Ct0, 0, 0, 0);
            Ct1 = __builtin_amdgcn_mfma_f32_32x32x16_bf16(A1, Btn, Ct1, 0, 0, 0);
        }
        s16x8 Bf[4], Bt[4];
        trans_tan(Cf0, Cf1, Ct0, Ct1, Bf, Bt);

#pragma unroll
        for (int L = 0; L < 3; ++L) {
            const int base = 2 + L * 10;
            Cf0 = zf(); Cf1 = zf(); Ct0 = zf(); Ct1 = zf();
            Cf0 = __builtin_amdgcn_mfma_f32_32x32x16_bf16(frag_of(fragLDS[(base + 4) * 64 + l]), Bone, Cf0, 0, 0, 0);
            Cf1 = __builtin_amdgcn_mfma_f32_32x32x16_bf16(frag_of(fragLDS[(base + 9) * 64 + l]), Bone, Cf1, 0, 0, 0);
#pragma unroll
            for (int b = 0; b < 4; ++b) {
                s16x8 A0 = frag_of(fragLDS[(base + 0 + b) * 64 + l]);
                s16x8 A1 = frag_of(fragLDS[(base + 5 + b) * 64 + l]);
                Cf0 = __builtin_amdgcn_mfma_f32_32x32x16_bf16(A0, Bf[b], Cf0, 0, 0, 0);
                Ct0 = __builtin_amdgcn_mfma_f32_32x32x16_bf16(A0, Bt[b], Ct0, 0, 0, 0);
                Cf1 = __builtin_amdgcn_mfma_f32_32x32x16_bf16(A1, Bf[b], Cf1, 0, 0, 0);
                Ct1 = __builtin_amdgcn_mfma_f32_32x32x16_bf16(A1, Bt[b], Ct1, 0, 0, 0);
            }
            trans_tan(Cf0, Cf1, Ct0, Ct1, Bf, Bt);
        }

        f32x16 Cof = zf(), Cot = zf();
#pragma unroll
        for (int b = 0; b < 4; ++b) {
            s16x8 Ao = frag_of(fragLDS[(32 + b) * 64 + l]);
            Cof = __builtin_amdgcn_mfma_f32_32x32x16_bf16(Ao, Bf[b], Cof, 0, 0, 0);
            Cot = __builtin_amdgcn_mfma_f32_32x32x16_bf16(Ao, Bt[b], Cot, 0, 0, 0);
        }
        if (h == 0) {
            Y_ws[point]  = Cof[0] + bout;
            dY_ws[point] = Cot[0];
        }
    }
}

// ================= Phase 3: residuals + reduction =================
// grid.x: path blocks (16), grid.y: step chunks of 10 (5)

extern "C" __global__ void __launch_bounds__(256)
fbsnn_phase3(const float* __restrict__ y_ws, const float* __restrict__ q_ws,
             const float* __restrict__ Y_ws, const float* __restrict__ dY_ws,
             const float* __restrict__ dW, float* __restrict__ out)
{
    const int p  = blockIdx.x * 256 + threadIdx.x;
    const int n0 = blockIdx.y * 10;

    float acc = 0.0f;
    float Yc  = Y_ws[n0 * NPATH + p];
#pragma unroll
    for (int k = 0; k < 10; ++k) {
        const int n = n0 + k;
        float q    = q_ws[n * NPATH + p];
        float dYc  = dY_ws[n * NPATH + p];
        float dws  = dW[n * NPATH + p] * SQRT_DT;
        float Yn   = Y_ws[(n + 1) * NPATH + p];
        float Ytil = fmaf(-q * q, DT_F, Yc) + (SIGMA_F * dYc) * dws;
        float r    = Yn - Ytil;
        acc = fmaf(r, r, acc);
        Yc = Yn;
    }
    if (blockIdx.y == 4) {
        float y50  = y_ws[NSTEP * NPATH + p];
        float dY50 = dY_ws[NSTEP * NPATH + p];
        float r1 = Yc - y50 * y50;
        float r2 = dY50 - 2.0f * y50;
        acc = fmaf(r1, r1, fmaf(r2, r2, acc));
    }

    float v = acc;
#pragma unroll
    for (int off = 32; off > 0; off >>= 1) v += __shfl_down(v, off, 64);
    if ((threadIdx.x & 63) == 0) atomicAdd(out, v * (1.0f / (float)NPATH));
}

// ================= host launch =================

extern "C" void kernel_launch(void* const* d_in, const int* in_sizes, int n_in,
                              void* d_out, int out_size, void* d_ws, size_t ws_size,
                              hipStream_t stream)
{
    const float* Y_Win  = (const float*)d_in[0];
    const float* Y_bin  = (const float*)d_in[1];
    const float* Y_Whid = (const float*)d_in[2];
    const float* Y_bhid = (const float*)d_in[3];
    const float* Y_Wout = (const float*)d_in[4];
    const float* Y_bout = (const float*)d_in[5];
    const float* q_Win  = (const float*)d_in[6];
    const float* q_bin  = (const float*)d_in[7];
    const float* q_Whid = (const float*)d_in[8];
    const float* q_bhid = (const float*)d_in[9];
    const float* q_Wout = (const float*)d_in[10];
    const float* q_bout = (const float*)d_in[11];
    const float* y0p    = (const float*)d_in[12];
    const float* dW     = (const float*)d_in[13];

    float* ws    = (float*)d_ws;
    float* y_ws  = ws;                          // 51*4096
    float* q_ws  = ws + 51 * NPATH;             // 50*4096
    float* Y_ws  = ws + 101 * NPATH;            // 51*4096
    float* dY_ws = ws + 152 * NPATH;            // 51*4096

    hipMemsetAsync(d_out, 0, sizeof(float), stream);

    fbsnn_phase1<<<dim3(128), dim3(64), 0, stream>>>(
        q_Win, q_bin, q_Whid, q_bhid, q_Wout, q_bout, y0p, dW, y_ws, q_ws);

    fbsnn_phase2<<<dim3(P2GRID), dim3(256), 0, stream>>>(
        Y_Win, Y_bin, Y_Whid, Y_bhid, Y_Wout, Y_bout, y_ws, Y_ws, dY_ws);

    fbsnn_phase3<<<dim3(NPATH / 256, 5), dim3(256), 0, stream>>>(
        y_ws, q_ws, Y_ws, dY_ws, dW, (float*)d_out);
}